// Round 1
// baseline (654.492 us; speedup 1.0000x reference)
//
#include <hip/hip_runtime.h>

// LSTM: T=512, B=4096, I=10, H=20. Gate order i,f,g,o (PyTorch).
// R3: gate-split 4-way. Each (batch,j) element is handled by 4 lanes
// (one per gate row) -> 4x wave count (5120 waves, 20/CU, 5/SIMD exact)
// and 4x less per-thread weight state (30 VGPRs vs 120 -> no spills).
// Lane layout: lane = 4*e + r, so gate partners sit at lane^1 / lane^2
// -> pure ds_swizzle gather (no cross-half ops). h is exchanged via a
// double-buffered 640B LDS array, one __syncthreads per step.
// Block = 320 thr = 5 waves = 4 whole batches; grid = 1024 = 4 blocks/CU.

#define T_STEPS 512
#define BATCH   4096
#define ISZ     10
#define HSZ     20
#define GPB     4      // batches per block
#define NTHR    320    // 4 gates * 20 j * 4 batches

typedef float v2f __attribute__((ext_vector_type(2)));

__device__ __forceinline__ v2f fma2(v2f a, v2f b, v2f c) {
    return __builtin_elementwise_fma(a, b, c);   // -> v_pk_fma_f32
}

#if defined(__has_builtin)
#if __has_builtin(__builtin_amdgcn_exp2f)
#define FAST_EXP2(x) __builtin_amdgcn_exp2f(x)
#endif
#if __has_builtin(__builtin_amdgcn_rcpf)
#define FAST_RCP(x) __builtin_amdgcn_rcpf(x)
#endif
#endif
#ifndef FAST_EXP2
#define FAST_EXP2(x) exp2f(x)
#endif
#ifndef FAST_RCP
#define FAST_RCP(x) (1.0f/(x))
#endif

// ds_swizzle BitMode: offset = (xor<<10)|(or<<5)|and
template<int PAT>
__device__ __forceinline__ float swzf(float v) {
    return __int_as_float(__builtin_amdgcn_ds_swizzle(__float_as_int(v), PAT));
}
#define SWZ_XOR1 0x041F
#define SWZ_XOR2 0x081F

__global__ __launch_bounds__(NTHR, 5) void lstm_fused_kernel(
    const float* __restrict__ x,    // [T, B, I]
    const float* __restrict__ h0,   // [B, H]
    const float* __restrict__ c0,   // [B, H]
    const float* __restrict__ Wih,  // [4H, I]
    const float* __restrict__ Whh,  // [4H, H]
    const float* __restrict__ bih,  // [4H]
    const float* __restrict__ bhh,  // [4H]
    float* __restrict__ out)        // [T*B*H] ++ [B*H] ++ [B*H]
{
    __shared__ __align__(16) float hbuf[2][GPB * HSZ];   // 640 B

    const int tid = threadIdx.x;
    const int r   = tid & 3;        // gate: 0=i,1=f,2=g,3=o
    const int E   = tid >> 2;       // element 0..79 within block
    const int bb  = E / HSZ;        // batch-in-block 0..3
    const int j   = E - bb * HSZ;   // 0..19
    const int gb  = blockIdx.x * GPB + bb;

    // unified activation: act(x) = A * rcp(1 + exp2(B*x)) + C
    // sigmoid: A=1, B=-1/ln2... (-1.4427), C=0 ; tanh: A=2, B=-2.8854, C=-1
    const float Bc = (r == 2) ? -2.8853900817779268f : -1.4426950408889634f;
    const float Ac = (r == 2) ? 2.0f : 1.0f;
    const float Cc = (r == 2) ? -1.0f : 0.0f;

    // this lane's single gate row
    const int row = r * HSZ + j;
    v2f wi[5], wh[10];
    {
        const v2f* wip = (const v2f*)(Wih + row * ISZ);   // 40B rows, 8B aligned
        const v2f* whp = (const v2f*)(Whh + row * HSZ);   // 80B rows, 8B aligned
#pragma unroll
        for (int k = 0; k < 5; ++k)  wi[k] = wip[k];
#pragma unroll
        for (int k = 0; k < 10; ++k) wh[k] = whp[k];
    }
    const float bias = bih[row] + bhh[row];

    float c = c0[(size_t)gb * HSZ + j];          // real only on r==0 lanes
    if (r == 0) hbuf[0][E] = h0[(size_t)gb * HSZ + j];

    const float* xbase = x + (size_t)gb * ISZ;
    float* outp = out + (size_t)gb * HSZ + j;

    // prefetch x[0], x[1] (PF=2: refill at step t loads x[t+2], ~2 steps slack)
    v2f nxA[5], nxB[5];
    {
        const v2f* x0p = (const v2f*)(xbase);
        const v2f* x1p = (const v2f*)(xbase + (size_t)BATCH * ISZ);
#pragma unroll
        for (int q = 0; q < 5; ++q) { nxA[q] = x0p[q]; nxB[q] = x1p[q]; }
    }

    __syncthreads();

    float hn = 0.0f;
    int cur = 0;

#define STEP(NX, TI)                                                          \
    {                                                                         \
        /* 1) h broadcast read (batch row, 2-way addr max -> conflict-free)*/ \
        const v2f* hrow = (const v2f*)(&hbuf[cur][bb * HSZ]);                 \
        v2f hv[10];                                                           \
        _Pragma("unroll")                                                     \
        for (int q = 0; q < 10; ++q) hv[q] = hrow[q];                         \
        /* 2) x-part MACs (independent of h -> hides LDS latency) */          \
        v2f a = {bias, 0.0f};                                                 \
        _Pragma("unroll")                                                     \
        for (int k = 0; k < 5; ++k) a = fma2(wi[k], NX[k], a);                \
        /* 3) refill this x slot with x[t+2] (clamped at tail) */             \
        {                                                                     \
            int tp = (TI) + 2; if (tp > T_STEPS - 1) tp = T_STEPS - 1;        \
            const v2f* xp = (const v2f*)(xbase + (size_t)tp * (BATCH*ISZ));   \
            _Pragma("unroll")                                                 \
            for (int q = 0; q < 5; ++q) NX[q] = xp[q];                        \
        }                                                                     \
        /* 4) h-part MACs */                                                  \
        _Pragma("unroll")                                                     \
        for (int k = 0; k < 10; ++k) a = fma2(wh[k], hv[k], a);               \
        const float g   = a.x + a.y;                                          \
        /* 5) own-gate activation (uniform code, per-lane constants) */       \
        const float act = Ac * FAST_RCP(1.0f + FAST_EXP2(g * Bc)) + Cc;       \
        /* 6) gather partners: r0 sees p1=sig(f), q0=tanh(g), q1=sig(o) */    \
        const float p1 = swzf<SWZ_XOR1>(act);                                 \
        const float q0 = swzf<SWZ_XOR2>(act);                                 \
        const float q1 = swzf<SWZ_XOR2>(p1);                                  \
        /* 7) c/h update -- valid on r==0, bounded junk elsewhere */          \
        c = __builtin_fmaf(p1, c, act * q0);                                  \
        const float th = 2.0f * FAST_RCP(1.0f +                               \
                         FAST_EXP2(c * -2.8853900817779268f)) - 1.0f;         \
        hn = q1 * th;                                                         \
        if (r == 0) {                                                         \
            hbuf[cur ^ 1][E] = hn;              /* contiguous 16B/wave */     \
            outp[(size_t)(TI) * (BATCH * HSZ)] = hn;                          \
        }                                                                     \
        __syncthreads();                                                      \
        cur ^= 1;                                                             \
    }

    for (int t = 0; t < T_STEPS; t += 2) {
        STEP(nxA, t)
        STEP(nxB, t + 1)
    }
#undef STEP

    if (r == 0) {
        const size_t tail = (size_t)T_STEPS * BATCH * HSZ;
        out[tail + (size_t)gb * HSZ + j] = hn;
        out[tail + (size_t)BATCH * HSZ + (size_t)gb * HSZ + j] = c;
    }
}

extern "C" void kernel_launch(void* const* d_in, const int* in_sizes, int n_in,
                              void* d_out, int out_size, void* d_ws, size_t ws_size,
                              hipStream_t stream) {
    const float* x   = (const float*)d_in[0];
    const float* h0  = (const float*)d_in[1];
    const float* c0  = (const float*)d_in[2];
    const float* Wih = (const float*)d_in[3];
    const float* Whh = (const float*)d_in[4];
    const float* bih = (const float*)d_in[5];
    const float* bhh = (const float*)d_in[6];
    float* out = (float*)d_out;

    const int nblk = BATCH / GPB;   // 1024 blocks = 4 per CU
    lstm_fused_kernel<<<nblk, NTHR, 0, stream>>>(x, h0, c0, Wih, Whh, bih, bhh, out);
}

// Round 3
// 595.965 us; speedup vs baseline: 1.0982x; 1.0982x over previous
//
#include <hip/hip_runtime.h>

// LSTM: T=512, B=4096, I=10, H=20. Gate order i,f,g,o (PyTorch).
// R5: R4's one-batch-per-wave 2-way gate split, hardened:
//   - FULL exec (no early return): lanes >=40 run with clamped j, stores
//     predicated. Cross-lane ops see exec = all 64 lanes.
//   - __shfl_xor(act,1) instead of raw ds_swizzle (same xor-1 partner).
//   - zero-cost compiler fences pin the wave-synchronous LDS h-exchange
//     (write at step t must precede read at t+1 across the unrolled loop).
// lane = 2*j + s: s=0 owns rows {i_j,f_j}, s=1 owns {g_j,o_j}.
// 4096 waves = 4 chains/SIMD, NO barriers, pk_fma kept (2 rows/lane).
// Block = 256 thr = 4 waves = 4 batches; grid = 1024 = 4 blocks/CU.

#define T_STEPS 512
#define BATCH   4096
#define ISZ     10
#define HSZ     20
#define WPB     4            // waves (= batches) per block
#define NTHR    (WPB * 64)

typedef float v2f __attribute__((ext_vector_type(2)));
typedef float v4f __attribute__((ext_vector_type(4)));

__device__ __forceinline__ v2f fma2(v2f a, v2f b, v2f c) {
    return __builtin_elementwise_fma(a, b, c);   // -> v_pk_fma_f32
}

#if defined(__has_builtin)
#if __has_builtin(__builtin_amdgcn_exp2f)
#define FAST_EXP2(x) __builtin_amdgcn_exp2f(x)
#endif
#if __has_builtin(__builtin_amdgcn_rcpf)
#define FAST_RCP(x) __builtin_amdgcn_rcpf(x)
#endif
#endif
#ifndef FAST_EXP2
#define FAST_EXP2(x) exp2f(x)
#endif
#ifndef FAST_RCP
#define FAST_RCP(x) (1.0f/(x))
#endif

#define MEMFENCE() __asm__ __volatile__("" ::: "memory")

__global__ __launch_bounds__(NTHR, 4) void lstm_fused_kernel(
    const float* __restrict__ x,    // [T, B, I]
    const float* __restrict__ h0,   // [B, H]
    const float* __restrict__ c0,   // [B, H]
    const float* __restrict__ Wih,  // [4H, I]
    const float* __restrict__ Whh,  // [4H, H]
    const float* __restrict__ bih,  // [4H]
    const float* __restrict__ bhh,  // [4H]
    float* __restrict__ out)        // [T*B*H] ++ [B*H] ++ [B*H]
{
    __shared__ __align__(16) float hbuf[WPB][HSZ];   // 80B rows, 16B aligned

    const int tid  = threadIdx.x;
    const int wid  = tid >> 6;
    const int lane = tid & 63;
    const int s    = lane & 1;              // 0:{i,f}  1:{g,o}
    const int jraw = lane >> 1;             // 0..31
    const bool live = (jraw < HSZ);
    const int j    = live ? jraw : (jraw - HSZ);   // lanes 40..63: benign dup
    const int gb   = blockIdx.x * WPB + wid;
    const bool st  = live && (s == 0);      // store-enable

    // slot0 activation: s0 -> sigmoid(i), s1 -> tanh(g).  slot1: sigmoid.
    const float B0 = s ? -2.8853900817779268f : -1.4426950408889634f;
    const float A0 = s ? 2.0f : 1.0f;
    const float C0 = s ? -1.0f : 0.0f;

    // this lane's two gate rows: row_k = (2s+k)*HSZ + j
    v2f wi[2][5], wh[2][10];
    float bias[2];
#pragma unroll
    for (int k = 0; k < 2; ++k) {
        const int row = (2 * s + k) * HSZ + j;
        const v2f* wip = (const v2f*)(Wih + row * ISZ);   // 40B rows, 8B aligned
        const v2f* whp = (const v2f*)(Whh + row * HSZ);   // 80B rows
#pragma unroll
        for (int q = 0; q < 5; ++q)  wi[k][q] = wip[q];
#pragma unroll
        for (int q = 0; q < 10; ++q) wh[k][q] = whp[q];
        bias[k] = bih[row] + bhh[row];
    }

    float c = c0[(size_t)gb * HSZ + j];
    if (st) hbuf[wid][j] = h0[(size_t)gb * HSZ + j];   // wave-sync init

    const float* xrow = x + (size_t)gb * ISZ;   // wave-uniform (one batch/wave)
    float* outp = out + (size_t)gb * HSZ + j;

    // x prefetch, 2 deep (refill at t loads x[t+2]); broadcast 40B loads
    v2f nxA[5], nxB[5];
    {
        const v2f* x0p = (const v2f*)(xrow);
        const v2f* x1p = (const v2f*)(xrow + (size_t)BATCH * ISZ);
#pragma unroll
        for (int q = 0; q < 5; ++q) { nxA[q] = x0p[q]; nxB[q] = x1p[q]; }
    }

    float hn = 0.0f;

#define STEP(NX, TI)                                                          \
    {                                                                         \
        MEMFENCE();  /* h-read below prior step's h-write */                  \
        /* 1) h broadcast read: whole wave reads same 80B -> conflict-free */ \
        const v4f* hq = (const v4f*)(&hbuf[wid][0]);                          \
        v4f h4[5];                                                            \
        _Pragma("unroll")                                                     \
        for (int m = 0; m < 5; ++m) h4[m] = hq[m];                            \
        /* 2) x-part MACs (independent of h -> hides LDS latency) */          \
        v2f a0 = {bias[0], 0.0f}, a1 = {bias[1], 0.0f};                       \
        _Pragma("unroll")                                                     \
        for (int q = 0; q < 5; ++q) {                                         \
            a0 = fma2(wi[0][q], NX[q], a0);                                   \
            a1 = fma2(wi[1][q], NX[q], a1);                                   \
        }                                                                     \
        /* 3) refill this x slot with x[t+2] (clamped at tail) */             \
        {                                                                     \
            int tp = (TI) + 2; if (tp > T_STEPS - 1) tp = T_STEPS - 1;        \
            const v2f* xp = (const v2f*)(xrow + (size_t)tp * (BATCH * ISZ));  \
            _Pragma("unroll")                                                 \
            for (int q = 0; q < 5; ++q) NX[q] = xp[q];                        \
        }                                                                     \
        /* 4) h-part MACs (packed) */                                         \
        _Pragma("unroll")                                                     \
        for (int m = 0; m < 5; ++m) {                                         \
            const v2f lo = {h4[m].x, h4[m].y};                                \
            const v2f hi = {h4[m].z, h4[m].w};                                \
            a0 = fma2(wh[0][2 * m], lo, a0);                                  \
            a0 = fma2(wh[0][2 * m + 1], hi, a0);                              \
            a1 = fma2(wh[1][2 * m], lo, a1);                                  \
            a1 = fma2(wh[1][2 * m + 1], hi, a1);                              \
        }                                                                     \
        const float g0 = a0.x + a0.y;                                         \
        const float g1 = a1.x + a1.y;                                         \
        /* 5) own activations: s0 {sig(i), sig(f)}, s1 {tanh(g), sig(o)} */   \
        const float act0 = A0 * FAST_RCP(1.0f + FAST_EXP2(g0 * B0)) + C0;     \
        const float act1 = FAST_RCP(1.0f +                                    \
                           FAST_EXP2(g1 * -1.4426950408889634f));             \
        /* 6) partner gather: two independent xor-1 shuffles, full exec */    \
        const float p0 = __shfl_xor(act0, 1);   /* s0 gets tanh(g) */         \
        const float p1 = __shfl_xor(act1, 1);   /* s0 gets sig(o)  */         \
        /* 7) c/h update -- valid on s==0, bounded junk elsewhere */          \
        c = __builtin_fmaf(act1, c, act0 * p0);                               \
        const float th = 2.0f * FAST_RCP(1.0f +                               \
                         FAST_EXP2(c * -2.8853900817779268f)) - 1.0f;         \
        hn = p1 * th;                                                         \
        if (st) {                                                             \
            hbuf[wid][j] = hn;                 /* wave-synchronous publish */ \
            outp[(size_t)(TI) * (BATCH * HSZ)] = hn;  /* 80B coalesced */     \
        }                                                                     \
        MEMFENCE();  /* h-write above next step's h-read */                   \
    }

    for (int t = 0; t < T_STEPS; t += 2) {
        STEP(nxA, t)
        STEP(nxB, t + 1)
    }
#undef STEP

    if (st) {
        const size_t tail = (size_t)T_STEPS * BATCH * HSZ;
        out[tail + (size_t)gb * HSZ + j] = hn;
        out[tail + (size_t)BATCH * HSZ + (size_t)gb * HSZ + j] = c;
    }
}

extern "C" void kernel_launch(void* const* d_in, const int* in_sizes, int n_in,
                              void* d_out, int out_size, void* d_ws, size_t ws_size,
                              hipStream_t stream) {
    const float* x   = (const float*)d_in[0];
    const float* h0  = (const float*)d_in[1];
    const float* c0  = (const float*)d_in[2];
    const float* Wih = (const float*)d_in[3];
    const float* Whh = (const float*)d_in[4];
    const float* bih = (const float*)d_in[5];
    const float* bhh = (const float*)d_in[6];
    float* out = (float*)d_out;

    const int nblk = BATCH / WPB;   // 1024 blocks = 4 per CU
    lstm_fused_kernel<<<nblk, NTHR, 0, stream>>>(x, h0, c0, Wih, Whh, bih, bhh, out);
}

// Round 4
// 498.830 us; speedup vs baseline: 1.3121x; 1.1947x over previous
//
#include <hip/hip_runtime.h>

// LSTM: T=512, B=4096, I=10, H=20. Gate order i,f,g,o (PyTorch).
// R6: R5 geometry/math (proven correct, absmax 0.00195), three fixes:
//  1. amdgpu_waves_per_eu(4,4): R5's compiler self-capped VGPR=64 (8-wave
//     target) and rematerialized the 60-VGPR weight set as in-loop loads.
//     Only 4 waves/SIMD exist (4096 waves / 1024 SIMDs) -> pin target to 4,
//     budget 128 VGPR, weights stay register-resident.
//  2. DPP quad_perm[1,0,3,2] (0xB1 = lane^1) replaces __shfl_xor
//     (ds_bpermute): 2-cy VALU swap instead of ~100cy LDS op in the
//     c-update dependency chain, twice per step.
//  3. asm "memory"-clobber fences -> wave_barrier + wavefront-scope
//     acq_rel fence (zero instructions; orders hbuf write(t) -> read(t+1)
//     without blocking remat/scheduling of unrelated loads).
// lane = 2*j + s: s=0 owns rows {i_j,f_j}, s=1 owns {g_j,o_j}; full exec;
// stores predicated. Block = 256 thr = 4 waves = 4 batches; grid = 1024.

#define T_STEPS 512
#define BATCH   4096
#define ISZ     10
#define HSZ     20
#define WPB     4            // waves (= batches) per block
#define NTHR    (WPB * 64)

typedef float v2f __attribute__((ext_vector_type(2)));
typedef float v4f __attribute__((ext_vector_type(4)));

__device__ __forceinline__ v2f fma2(v2f a, v2f b, v2f c) {
    return __builtin_elementwise_fma(a, b, c);   // -> v_pk_fma_f32
}

#if defined(__has_builtin)
#if __has_builtin(__builtin_amdgcn_exp2f)
#define FAST_EXP2(x) __builtin_amdgcn_exp2f(x)
#endif
#if __has_builtin(__builtin_amdgcn_rcpf)
#define FAST_RCP(x) __builtin_amdgcn_rcpf(x)
#endif
#endif
#ifndef FAST_EXP2
#define FAST_EXP2(x) exp2f(x)
#endif
#ifndef FAST_RCP
#define FAST_RCP(x) (1.0f/(x))
#endif

// lane^1 partner swap via DPP quad_perm [1,0,3,2] -- 2-cycle VALU op.
__device__ __forceinline__ float dpp_xor1(float v) {
    return __int_as_float(__builtin_amdgcn_update_dpp(
        0, __float_as_int(v), 0xB1, 0xF, 0xF, true));
}

// Wave-synchronous LDS ordering: write(t) must be visible to the whole
// wave's read(t+1). Zero-instruction on gfx950 (wavefront scope).
#define HSYNC()                                                   \
    do {                                                          \
        __builtin_amdgcn_wave_barrier();                          \
        __builtin_amdgcn_fence(__ATOMIC_ACQ_REL, "wavefront");    \
        __builtin_amdgcn_wave_barrier();                          \
    } while (0)

__global__ __launch_bounds__(NTHR)
__attribute__((amdgpu_waves_per_eu(4, 4)))
void lstm_fused_kernel(
    const float* __restrict__ x,    // [T, B, I]
    const float* __restrict__ h0,   // [B, H]
    const float* __restrict__ c0,   // [B, H]
    const float* __restrict__ Wih,  // [4H, I]
    const float* __restrict__ Whh,  // [4H, H]
    const float* __restrict__ bih,  // [4H]
    const float* __restrict__ bhh,  // [4H]
    float* __restrict__ out)        // [T*B*H] ++ [B*H] ++ [B*H]
{
    __shared__ __align__(16) float hbuf[WPB][HSZ];   // 80B rows, 16B aligned

    const int tid  = threadIdx.x;
    const int wid  = tid >> 6;
    const int lane = tid & 63;
    const int s    = lane & 1;              // 0:{i,f}  1:{g,o}
    const int jraw = lane >> 1;             // 0..31
    const bool live = (jraw < HSZ);
    const int j    = live ? jraw : (jraw - HSZ);   // lanes 40..63: benign dup
    const int gb   = blockIdx.x * WPB + wid;
    const bool st  = live && (s == 0);      // store-enable

    // slot0 activation: s0 -> sigmoid(i), s1 -> tanh(g).  slot1: sigmoid.
    const float B0 = s ? -2.8853900817779268f : -1.4426950408889634f;
    const float A0 = s ? 2.0f : 1.0f;
    const float C0 = s ? -1.0f : 0.0f;

    // this lane's two gate rows: row_k = (2s+k)*HSZ + j
    v2f wi[2][5], wh[2][10];
    float bias[2];
#pragma unroll
    for (int k = 0; k < 2; ++k) {
        const int row = (2 * s + k) * HSZ + j;
        const v2f* wip = (const v2f*)(Wih + row * ISZ);   // 40B rows, 8B aligned
        const v2f* whp = (const v2f*)(Whh + row * HSZ);   // 80B rows
#pragma unroll
        for (int q = 0; q < 5; ++q)  wi[k][q] = wip[q];
#pragma unroll
        for (int q = 0; q < 10; ++q) wh[k][q] = whp[q];
        bias[k] = bih[row] + bhh[row];
    }

    float c = c0[(size_t)gb * HSZ + j];
    if (st) hbuf[wid][j] = h0[(size_t)gb * HSZ + j];   // wave-sync init
    HSYNC();

    const float* xrow = x + (size_t)gb * ISZ;   // wave-uniform (one batch/wave)
    float* outp = out + (size_t)gb * HSZ + j;

    // x prefetch, 2 deep (refill at t loads x[t+2]); broadcast 40B loads
    v2f nxA[5], nxB[5];
    {
        const v2f* x0p = (const v2f*)(xrow);
        const v2f* x1p = (const v2f*)(xrow + (size_t)BATCH * ISZ);
#pragma unroll
        for (int q = 0; q < 5; ++q) { nxA[q] = x0p[q]; nxB[q] = x1p[q]; }
    }

    float hn = 0.0f;

#define STEP(NX, TI)                                                          \
    {                                                                         \
        /* 1) h broadcast read: whole wave reads same 80B -> conflict-free */ \
        const v4f* hq = (const v4f*)(&hbuf[wid][0]);                          \
        v4f h4[5];                                                            \
        _Pragma("unroll")                                                     \
        for (int m = 0; m < 5; ++m) h4[m] = hq[m];                            \
        /* 2) x-part MACs (independent of h -> hides LDS latency) */          \
        v2f a0 = {bias[0], 0.0f}, a1 = {bias[1], 0.0f};                       \
        _Pragma("unroll")                                                     \
        for (int q = 0; q < 5; ++q) {                                         \
            a0 = fma2(wi[0][q], NX[q], a0);                                   \
            a1 = fma2(wi[1][q], NX[q], a1);                                   \
        }                                                                     \
        /* 3) refill this x slot with x[t+2] (clamped at tail) */             \
        {                                                                     \
            int tp = (TI) + 2; if (tp > T_STEPS - 1) tp = T_STEPS - 1;        \
            const v2f* xp = (const v2f*)(xrow + (size_t)tp * (BATCH * ISZ));  \
            _Pragma("unroll")                                                 \
            for (int q = 0; q < 5; ++q) NX[q] = xp[q];                        \
        }                                                                     \
        /* 4) h-part MACs (packed) */                                         \
        _Pragma("unroll")                                                     \
        for (int m = 0; m < 5; ++m) {                                         \
            const v2f lo = {h4[m].x, h4[m].y};                                \
            const v2f hi = {h4[m].z, h4[m].w};                                \
            a0 = fma2(wh[0][2 * m], lo, a0);                                  \
            a0 = fma2(wh[0][2 * m + 1], hi, a0);                              \
            a1 = fma2(wh[1][2 * m], lo, a1);                                  \
            a1 = fma2(wh[1][2 * m + 1], hi, a1);                              \
        }                                                                     \
        const float g0 = a0.x + a0.y;                                         \
        const float g1 = a1.x + a1.y;                                         \
        /* 5) own activations: s0 {sig(i), sig(f)}, s1 {tanh(g), sig(o)} */   \
        const float act0 = A0 * FAST_RCP(1.0f + FAST_EXP2(g0 * B0)) + C0;     \
        const float act1 = FAST_RCP(1.0f +                                    \
                           FAST_EXP2(g1 * -1.4426950408889634f));             \
        /* 6) partner gather: two independent DPP lane^1 swaps (VALU) */      \
        const float p0 = dpp_xor1(act0);   /* s0 gets tanh(g) */              \
        const float p1 = dpp_xor1(act1);   /* s0 gets sig(o)  */              \
        /* 7) c/h update -- valid on s==0, bounded junk elsewhere */          \
        c = __builtin_fmaf(act1, c, act0 * p0);                               \
        const float th = 2.0f * FAST_RCP(1.0f +                               \
                         FAST_EXP2(c * -2.8853900817779268f)) - 1.0f;         \
        hn = p1 * th;                                                         \
        if (st) {                                                             \
            hbuf[wid][j] = hn;                 /* wave-synchronous publish */ \
            outp[(size_t)(TI) * (BATCH * HSZ)] = hn;  /* 80B coalesced */     \
        }                                                                     \
        HSYNC();  /* order h-write(t) before h-read(t+1), zero-cost */        \
    }

    for (int t = 0; t < T_STEPS; t += 2) {
        STEP(nxA, t)
        STEP(nxB, t + 1)
    }
#undef STEP

    if (st) {
        const size_t tail = (size_t)T_STEPS * BATCH * HSZ;
        out[tail + (size_t)gb * HSZ + j] = hn;
        out[tail + (size_t)BATCH * HSZ + (size_t)gb * HSZ + j] = c;
    }
}

extern "C" void kernel_launch(void* const* d_in, const int* in_sizes, int n_in,
                              void* d_out, int out_size, void* d_ws, size_t ws_size,
                              hipStream_t stream) {
    const float* x   = (const float*)d_in[0];
    const float* h0  = (const float*)d_in[1];
    const float* c0  = (const float*)d_in[2];
    const float* Wih = (const float*)d_in[3];
    const float* Whh = (const float*)d_in[4];
    const float* bih = (const float*)d_in[5];
    const float* bhh = (const float*)d_in[6];
    float* out = (float*)d_out;

    const int nblk = BATCH / WPB;   // 1024 blocks = 4 per CU
    lstm_fused_kernel<<<nblk, NTHR, 0, stream>>>(x, h0, c0, Wih, Whh, bih, bhh, out);
}

// Round 5
// 495.040 us; speedup vs baseline: 1.3221x; 1.0077x over previous
//
#include <hip/hip_runtime.h>

// LSTM: T=512, B=4096, I=10, H=20. Gate order i,f,g,o (PyTorch).
// R7: R6 structure (proven correct), three codegen fixes:
//  1. asm-PIN the weight/bias registers: R6's allocator kept VGPR=64 and
//     rematerialized ~30 weight loads per step inside the loop. An asm
//     "+v" def cannot be rematerialized -> weights stay resident.
//  2. x refills forced onto VMEM (divergent opaque zero in the pointer):
//     R6 scalarized them to SMEM (SGPR=112), and SMEM shares lgkmcnt with
//     LDS (OOO completion -> lgkmcnt(0) waits), dragging x latency into
//     the h-recurrence chain. VMEM uses vmcnt -> PF=2 slack restored.
//  3. HSYNC fence -> single wave_barrier() (zero-byte scheduling barrier;
//     HW keeps one wave's DS ops in order, so no fence/waitcnt needed).
// lane = 2*j + s: s=0 owns rows {i_j,f_j}, s=1 owns {g_j,o_j}; full exec;
// stores predicated. Block = 256 thr = 4 waves = 4 batches; grid = 1024.

#define T_STEPS 512
#define BATCH   4096
#define ISZ     10
#define HSZ     20
#define WPB     4            // waves (= batches) per block
#define NTHR    (WPB * 64)

typedef float v2f __attribute__((ext_vector_type(2)));
typedef float v4f __attribute__((ext_vector_type(4)));

__device__ __forceinline__ v2f fma2(v2f a, v2f b, v2f c) {
    return __builtin_elementwise_fma(a, b, c);   // -> v_pk_fma_f32
}

#if defined(__has_builtin)
#if __has_builtin(__builtin_amdgcn_exp2f)
#define FAST_EXP2(x) __builtin_amdgcn_exp2f(x)
#endif
#if __has_builtin(__builtin_amdgcn_rcpf)
#define FAST_RCP(x) __builtin_amdgcn_rcpf(x)
#endif
#endif
#ifndef FAST_EXP2
#define FAST_EXP2(x) exp2f(x)
#endif
#ifndef FAST_RCP
#define FAST_RCP(x) (1.0f/(x))
#endif

// Pin a value into VGPR(s): asm-defined values cannot be rematerialized.
#define PIN(v) asm volatile("" : "+v"(v))

// lane^1 partner swap via DPP quad_perm [1,0,3,2] -- 2-cycle VALU op.
__device__ __forceinline__ float dpp_xor1(float v) {
    return __int_as_float(__builtin_amdgcn_update_dpp(
        0, __float_as_int(v), 0xB1, 0xF, 0xF, true));
}

__global__ __launch_bounds__(NTHR)
__attribute__((amdgpu_waves_per_eu(4, 4)))
void lstm_fused_kernel(
    const float* __restrict__ x,    // [T, B, I]
    const float* __restrict__ h0,   // [B, H]
    const float* __restrict__ c0,   // [B, H]
    const float* __restrict__ Wih,  // [4H, I]
    const float* __restrict__ Whh,  // [4H, H]
    const float* __restrict__ bih,  // [4H]
    const float* __restrict__ bhh,  // [4H]
    float* __restrict__ out)        // [T*B*H] ++ [B*H] ++ [B*H]
{
    __shared__ __align__(16) float hbuf[WPB][HSZ];   // 80B rows, 16B aligned

    const int tid  = threadIdx.x;
    const int wid  = tid >> 6;
    const int lane = tid & 63;
    const int s    = lane & 1;              // 0:{i,f}  1:{g,o}
    const int jraw = lane >> 1;             // 0..31
    const bool live = (jraw < HSZ);
    const int j    = live ? jraw : (jraw - HSZ);   // lanes 40..63: benign dup
    const int gb   = blockIdx.x * WPB + wid;
    const bool st  = live && (s == 0);      // store-enable

    // slot0 activation: s0 -> sigmoid(i), s1 -> tanh(g).  slot1: sigmoid.
    const float B0 = s ? -2.8853900817779268f : -1.4426950408889634f;
    const float A0 = s ? 2.0f : 1.0f;
    const float C0 = s ? -1.0f : 0.0f;

    // this lane's two gate rows: row_k = (2s+k)*HSZ + j
    v2f wi[2][5], wh[2][10];
    float bias[2];
#pragma unroll
    for (int k = 0; k < 2; ++k) {
        const int row = (2 * s + k) * HSZ + j;
        const v2f* wip = (const v2f*)(Wih + row * ISZ);   // 40B rows, 8B aligned
        const v2f* whp = (const v2f*)(Whh + row * HSZ);   // 80B rows
#pragma unroll
        for (int q = 0; q < 5; ++q)  wi[k][q] = wip[q];
#pragma unroll
        for (int q = 0; q < 10; ++q) wh[k][q] = whp[q];
        bias[k] = bih[row] + bhh[row];
    }
    // force register residency (no in-loop remat)
#pragma unroll
    for (int k = 0; k < 2; ++k) {
#pragma unroll
        for (int q = 0; q < 5; ++q)  PIN(wi[k][q]);
#pragma unroll
        for (int q = 0; q < 10; ++q) PIN(wh[k][q]);
        PIN(bias[k]);
    }

    float c = c0[(size_t)gb * HSZ + j];
    if (st) hbuf[wid][j] = h0[(size_t)gb * HSZ + j];   // wave-sync init
    __builtin_amdgcn_wave_barrier();

    // opaque divergent 0 -> x pointer is non-uniform -> VMEM (vmcnt) path,
    // decoupled from the LDS lgkmcnt waits in the recurrence chain.
    int dz;
    asm volatile("v_mov_b32 %0, 0" : "=v"(dz));
    const float* xrow = x + (size_t)gb * ISZ + dz;
    float* outp = out + (size_t)gb * HSZ + j;

    // x prefetch, 2 deep (refill at t loads x[t+2]); broadcast 40B loads
    v2f nxA[5], nxB[5];
    {
        const v2f* x0p = (const v2f*)(xrow);
        const v2f* x1p = (const v2f*)(xrow + (size_t)BATCH * ISZ);
#pragma unroll
        for (int q = 0; q < 5; ++q) { nxA[q] = x0p[q]; nxB[q] = x1p[q]; }
    }

    float hn = 0.0f;

#define STEP(NX, TI)                                                          \
    {                                                                         \
        /* 1) h broadcast read: whole wave reads same 80B -> conflict-free */ \
        const v4f* hq = (const v4f*)(&hbuf[wid][0]);                          \
        v4f h4[5];                                                            \
        _Pragma("unroll")                                                     \
        for (int m = 0; m < 5; ++m) h4[m] = hq[m];                            \
        /* 2) x-part MACs (independent of h -> hides LDS latency) */          \
        v2f a0 = {bias[0], 0.0f}, a1 = {bias[1], 0.0f};                       \
        _Pragma("unroll")                                                     \
        for (int q = 0; q < 5; ++q) {                                         \
            a0 = fma2(wi[0][q], NX[q], a0);                                   \
            a1 = fma2(wi[1][q], NX[q], a1);                                   \
        }                                                                     \
        /* 3) refill this x slot with x[t+2] (clamped at tail, VMEM) */       \
        {                                                                     \
            int tp = (TI) + 2; if (tp > T_STEPS - 1) tp = T_STEPS - 1;        \
            const v2f* xp = (const v2f*)(xrow + (size_t)tp * (BATCH * ISZ));  \
            _Pragma("unroll")                                                 \
            for (int q = 0; q < 5; ++q) NX[q] = xp[q];                        \
        }                                                                     \
        /* 4) h-part MACs (packed) */                                         \
        _Pragma("unroll")                                                     \
        for (int m = 0; m < 5; ++m) {                                         \
            const v2f lo = {h4[m].x, h4[m].y};                                \
            const v2f hi = {h4[m].z, h4[m].w};                                \
            a0 = fma2(wh[0][2 * m], lo, a0);                                  \
            a0 = fma2(wh[0][2 * m + 1], hi, a0);                              \
            a1 = fma2(wh[1][2 * m], lo, a1);                                  \
            a1 = fma2(wh[1][2 * m + 1], hi, a1);                              \
        }                                                                     \
        const float g0 = a0.x + a0.y;                                         \
        const float g1 = a1.x + a1.y;                                         \
        /* 5) own activations: s0 {sig(i), sig(f)}, s1 {tanh(g), sig(o)} */   \
        const float act0 = A0 * FAST_RCP(1.0f + FAST_EXP2(g0 * B0)) + C0;     \
        const float act1 = FAST_RCP(1.0f +                                    \
                           FAST_EXP2(g1 * -1.4426950408889634f));             \
        /* 6) partner gather: two independent DPP lane^1 swaps (VALU) */      \
        const float p0 = dpp_xor1(act0);   /* s0 gets tanh(g) */              \
        const float p1 = dpp_xor1(act1);   /* s0 gets sig(o)  */              \
        /* 7) c/h update -- valid on s==0, bounded junk elsewhere */          \
        c = __builtin_fmaf(act1, c, act0 * p0);                               \
        const float th = 2.0f * FAST_RCP(1.0f +                               \
                         FAST_EXP2(c * -2.8853900817779268f)) - 1.0f;         \
        hn = p1 * th;                                                         \
        if (st) {                                                             \
            hbuf[wid][j] = hn;                 /* wave-synchronous publish */ \
            outp[(size_t)(TI) * (BATCH * HSZ)] = hn;  /* 80B coalesced */     \
        }                                                                     \
        __builtin_amdgcn_wave_barrier();  /* order write(t) < read(t+1) */    \
    }

    for (int t = 0; t < T_STEPS; t += 2) {
        STEP(nxA, t)
        STEP(nxB, t + 1)
    }
#undef STEP

    if (st) {
        const size_t tail = (size_t)T_STEPS * BATCH * HSZ;
        out[tail + (size_t)gb * HSZ + j] = hn;
        out[tail + (size_t)BATCH * HSZ + (size_t)gb * HSZ + j] = c;
    }
}

extern "C" void kernel_launch(void* const* d_in, const int* in_sizes, int n_in,
                              void* d_out, int out_size, void* d_ws, size_t ws_size,
                              hipStream_t stream) {
    const float* x   = (const float*)d_in[0];
    const float* h0  = (const float*)d_in[1];
    const float* c0  = (const float*)d_in[2];
    const float* Wih = (const float*)d_in[3];
    const float* Whh = (const float*)d_in[4];
    const float* bih = (const float*)d_in[5];
    const float* bhh = (const float*)d_in[6];
    float* out = (float*)d_out;

    const int nblk = BATCH / WPB;   // 1024 blocks = 4 per CU
    lstm_fused_kernel<<<nblk, NTHR, 0, stream>>>(x, h0, c0, Wih, Whh, bih, bhh, out);
}